// Round 6
// baseline (540.658 us; speedup 1.0000x reference)
//
#include <hip/hip_runtime.h>
#include <stdint.h>
#include <stddef.h>

typedef int v4i  __attribute__((ext_vector_type(4)));
typedef int v16i __attribute__((ext_vector_type(16)));

#define GELU_A   (-0.2888f)
#define GELU_B   (-1.769f)
#define INV_SQRT2 0.70710678118654752440f

// scalar slots (new layout for 2-memset init):
//  sc[0]=enc(xmin)  sc[1]=enc(gmin)            [init 0xFFFFFFFF]
//  sc[2]=enc(xmax)  sc[3]=|w1|max bits  sc[4]=|w2|max bits  sc[5]=enc(gmax) [init 0]

// ---- order-preserving float<->uint encoding for atomic min/max ----
__device__ __forceinline__ unsigned enc_f(float f){
  unsigned u = __float_as_uint(f);
  return (u & 0x80000000u) ? ~u : (u | 0x80000000u);
}
__device__ __forceinline__ float dec_f(unsigned e){
  unsigned u = (e & 0x80000000u) ? (e & 0x7FFFFFFFu) : ~e;
  return __uint_as_float(u);
}

__device__ __forceinline__ float int_gelu_f(float x){
  float t = x * INV_SQRT2;
  float at = fminf(fabsf(t), 1.769f);
  float u = at + GELU_B;                 // in [-1.769, 0]
  float p = GELU_A * (u * u) + 1.0f;
  float L = (t > 0.0f) ? p : ((t < 0.0f) ? -p : 0.0f);
  return x * 0.5f * (1.0f + L);
}

// blocks [0,1024): x min/max; [1024,1152): absmax w1 -> sc[3]; [1152,1280): absmax w2 -> sc[4]
__global__ __launch_bounds__(256) void reduce_stats(
    const float4* __restrict__ x, int nx4,
    const float4* __restrict__ w1, int n14,
    const float4* __restrict__ w2, int n24,
    unsigned* __restrict__ sc)
{
  __shared__ float ra[256], rb[256];
  const int tid = threadIdx.x;
  const int b = blockIdx.x;
  if (b < 1024){
    float lmin = 3.4e38f, lmax = -3.4e38f;
    for (long i = (long)b * 256 + tid; i < nx4; i += 1024L * 256L){
      float4 v = x[i];
      lmin = fminf(lmin, fminf(fminf(v.x, v.y), fminf(v.z, v.w)));
      lmax = fmaxf(lmax, fmaxf(fmaxf(v.x, v.y), fmaxf(v.z, v.w)));
    }
    ra[tid] = lmin; rb[tid] = lmax;
    __syncthreads();
    for (int s = 128; s > 0; s >>= 1){
      if (tid < s){ ra[tid] = fminf(ra[tid], ra[tid + s]); rb[tid] = fmaxf(rb[tid], rb[tid + s]); }
      __syncthreads();
    }
    if (tid == 0){
      atomicMin(&sc[0], enc_f(ra[0]));
      atomicMax(&sc[2], enc_f(rb[0]));
    }
  } else {
    const float4* w; int n4; int slot; int bl;
    if (b < 1152){ w = w1; n4 = n14; slot = 3; bl = b - 1024; }
    else         { w = w2; n4 = n24; slot = 4; bl = b - 1152; }
    float la = 0.0f;
    for (long i = (long)bl * 256 + tid; i < n4; i += 128L * 256L){
      float4 v = w[i];
      la = fmaxf(la, fmaxf(fmaxf(fabsf(v.x), fabsf(v.y)), fmaxf(fabsf(v.z), fabsf(v.w))));
    }
    ra[tid] = la;
    __syncthreads();
    for (int s = 128; s > 0; s >>= 1){
      if (tid < s) ra[tid] = fmaxf(ra[tid], ra[tid + s]);
      __syncthreads();
    }
    if (tid == 0) atomicMax(&sc[slot], __float_as_uint(ra[0]));
  }
}

// fused: blocks [0,2048) act-quant x -> qx ((q-128) int8, packed u32);
//        blocks [2048, 2048+H+D) weight-quant rows (+row sums)
__global__ __launch_bounds__(256) void quant_all(
    const float4* __restrict__ x, unsigned* __restrict__ qx, long nx4,
    const float* __restrict__ w1, const float* __restrict__ w2,
    int8_t* __restrict__ qw1, int8_t* __restrict__ qw2,
    int* __restrict__ rs1, int* __restrict__ rs2,
    const unsigned* __restrict__ sc, int H, int D)
{
  const int tid = threadIdx.x;
  const int b = blockIdx.x;
  if (b < 2048){
    const float vmin = dec_f(sc[0]);
    const float vmax = dec_f(sc[2]);
    const float s  = fmaxf(vmax - vmin, 1e-8f) / 255.0f;
    const float zp = rintf(-vmin / s);
    for (long i = (long)b * 256 + tid; i < nx4; i += 2048L * 256L){
      float4 v = x[i];
      int q0 = (int)fminf(fmaxf(rintf(v.x / s) + zp, 0.0f), 255.0f) - 128;
      int q1 = (int)fminf(fmaxf(rintf(v.y / s) + zp, 0.0f), 255.0f) - 128;
      int q2 = (int)fminf(fmaxf(rintf(v.z / s) + zp, 0.0f), 255.0f) - 128;
      int q3 = (int)fminf(fmaxf(rintf(v.w / s) + zp, 0.0f), 255.0f) - 128;
      qx[i] = ((unsigned)(q0 & 255)) | ((unsigned)(q1 & 255) << 8) |
              ((unsigned)(q2 & 255) << 16) | ((unsigned)(q3 & 255) << 24);
    }
  } else {
    __shared__ int red[256];
    const int wb = b - 2048;
    const float* w; int8_t* q; int* rs; int K; int n; float s;
    if (wb < H){ w = w1; q = qw1; rs = rs1; K = D; n = wb;
                 s = fmaxf(__uint_as_float(sc[3]), 1e-8f) / 127.0f; }
    else       { w = w2; q = qw2; rs = rs2; K = H; n = wb - H;
                 s = fmaxf(__uint_as_float(sc[4]), 1e-8f) / 127.0f; }
    int sum = 0;
    for (int k = tid; k < K; k += 256){
      float v = w[(size_t)n * K + k];
      float qf = fminf(fmaxf(rintf(v / s), -128.0f), 127.0f);
      int qi = (int)qf;
      q[(size_t)n * K + k] = (int8_t)qi;
      sum += qi;
    }
    red[tid] = sum;
    __syncthreads();
    for (int st = 128; st > 0; st >>= 1){
      if (tid < st) red[tid] += red[tid + st];
      __syncthreads();
    }
    if (tid == 0) rs[n] = red[0];
  }
}

// MODE 0: h->gelu-> g min/max atomics only (no store)
// MODE 2: h->gelu-> quantize with g stats -> store int8 (q-128)
// MODE 1: h + bias -> store fp32 out
//
// Barrier-free, LDS-free K-loop: 128x128 tile, 4 waves each 64x64 (2x2 of
// mfma_i32_32x32x32_i8). All fragments loaded DIRECTLY global->VGPR from 4
// per-lane base pointers with compile-time immediate offsets (K template,
// fully unrolled -> zero in-loop address VALU, pure load/MFMA dataflow the
// compiler pipelines with fine-grained vmcnt(N)). Reuse via L1 (16KB unique
// per block-iter) and L2 (whole B matrix = 2.4MB fits each XCD's 4MB L2).
template<int K, int MODE>
__global__ __launch_bounds__(256, 3) void gemm_i8(
    const int8_t* __restrict__ A, const int8_t* __restrict__ Bm,
    const int* __restrict__ rowsum, const float* __restrict__ bias,
    void* __restrict__ Cout, int M, int N,
    unsigned* __restrict__ sc)
{
  const int tid  = threadIdx.x;
  const int lane = tid & 63;
  const int wave = tid >> 6;
  const int l31  = lane & 31;
  const int kh   = lane >> 5;          // 0/1 : which 16B half of a 32-k block
  const int n0   = blockIdx.x * 128;
  const int m0   = blockIdx.y * 128;
  const int wm   = (wave & 1) * 64;
  const int wn   = (wave >> 1) * 64;

  // per-lane fragment base pointers (A rows clamped for the M tail)
  const int8_t* ap[2];
  const int8_t* bp[2];
#pragma unroll
  for (int i = 0; i < 2; i++){
    int ra = m0 + wm + i * 32 + l31; if (ra >= M) ra = M - 1;
    ap[i] = A  + (size_t)ra * K + kh * 16;
    bp[i] = Bm + (size_t)(n0 + wn + i * 32 + l31) * K + kh * 16;
  }

  v16i acc[2][2] = {};

#pragma unroll
  for (int kt = 0; kt < K / 64; kt++){
    v4i af[2][2], bf[2][2];              // [kk][i]
#pragma unroll
    for (int kk = 0; kk < 2; kk++){
#pragma unroll
      for (int i = 0; i < 2; i++){
        af[kk][i] = *(const v4i*)(ap[i] + kt * 64 + kk * 32);
        bf[kk][i] = *(const v4i*)(bp[i] + kt * 64 + kk * 32);
      }
    }
#pragma unroll
    for (int kk = 0; kk < 2; kk++)
#pragma unroll
      for (int mi = 0; mi < 2; mi++)
#pragma unroll
        for (int nj = 0; nj < 2; nj++)
          acc[mi][nj] = __builtin_amdgcn_mfma_i32_32x32x32_i8(af[kk][mi], bf[kk][nj], acc[mi][nj], 0, 0, 0);
  }

  // epilogue scalars
  float s_h, off_h;
  if constexpr (MODE == 1){
    float gmin = dec_f(sc[1]), gmax = dec_f(sc[5]);
    float sg = fmaxf(gmax - gmin, 1e-8f) / 255.0f;
    float zp = rintf(-gmin / sg);
    float sw = fmaxf(__uint_as_float(sc[4]), 1e-8f) / 127.0f;
    s_h = sg * sw; off_h = 128.0f - zp;
  } else {
    float xmin = dec_f(sc[0]), xmax = dec_f(sc[2]);
    float sx = fmaxf(xmax - xmin, 1e-8f) / 255.0f;
    float zp = rintf(-xmin / sx);
    float sw = fmaxf(__uint_as_float(sc[3]), 1e-8f) / 127.0f;
    s_h = sx * sw; off_h = 128.0f - zp;
  }
  float qs = 1.0f, qzp = 0.0f;
  if constexpr (MODE == 2){
    float gmin = dec_f(sc[1]), gmax = dec_f(sc[5]);
    qs = fmaxf(gmax - gmin, 1e-8f) / 255.0f;
    qzp = rintf(-gmin / qs);
  }

  // C/D 32x32 layout: col = lane&31, row = (reg&3) + 8*(reg>>2) + 4*(lane>>5)
  float lmin = 3.4e38f, lmax = -3.4e38f;
#pragma unroll
  for (int nj = 0; nj < 2; nj++){
    const int n = n0 + wn + nj * 32 + l31;
    const float rsv = off_h * (float)rowsum[n];
    const float bv = bias[n];
#pragma unroll
    for (int mi = 0; mi < 2; mi++){
      const int mbase = m0 + wm + mi * 32 + 4 * kh;
#pragma unroll
      for (int r = 0; r < 16; r++){
        const int m = mbase + (r & 3) + 8 * (r >> 2);
        if (m < M){
          float h = s_h * ((float)acc[mi][nj][r] + rsv) + bv;
          if constexpr (MODE == 0){
            float gv = int_gelu_f(h);
            lmin = fminf(lmin, gv); lmax = fmaxf(lmax, gv);
          } else if constexpr (MODE == 2){
            float gv = int_gelu_f(h);
            float qf = fminf(fmaxf(rintf(gv / qs) + qzp, 0.0f), 255.0f);
            ((int8_t*)Cout)[(size_t)m * N + n] = (int8_t)((int)qf - 128);
          } else {
            ((float*)Cout)[(size_t)m * N + n] = h;
          }
        }
      }
    }
  }

  if constexpr (MODE == 0){
    __shared__ float redA[256], redB[256];
    redA[tid] = lmin; redB[tid] = lmax;
    __syncthreads();
    for (int st = 128; st > 0; st >>= 1){
      if (tid < st){
        redA[tid] = fminf(redA[tid], redA[tid + st]);
        redB[tid] = fmaxf(redB[tid], redB[tid + st]);
      }
      __syncthreads();
    }
    if (tid == 0){
      atomicMin(&sc[1], enc_f(redA[0]));
      atomicMax(&sc[5], enc_f(redB[0]));
    }
  }
}

extern "C" void kernel_launch(void* const* d_in, const int* in_sizes, int n_in,
                              void* d_out, int out_size, void* d_ws, size_t ws_size,
                              hipStream_t stream)
{
  const float* x  = (const float*)d_in[0];
  const float* w1 = (const float*)d_in[1];
  const float* b1 = (const float*)d_in[2];
  const float* w2 = (const float*)d_in[3];
  const float* b2 = (const float*)d_in[4];
  float* out = (float*)d_out;

  const int H = in_sizes[2];            // 3072
  const int D = in_sizes[4];            // 768
  const int M = in_sizes[0] / D;        // 12608

  char* ws = (char*)d_ws;
  unsigned* sc = (unsigned*)ws;
  size_t off = 256;
  int8_t* qx  = (int8_t*)(ws + off); off += (size_t)M * D;   // 9.68 MB
  int8_t* qw1 = (int8_t*)(ws + off); off += (size_t)H * D;   // 2.36 MB
  int8_t* qw2 = (int8_t*)(ws + off); off += (size_t)D * H;   // 2.36 MB
  int* rs1 = (int*)(ws + off); off += (size_t)H * 4;
  int* rs2 = (int*)(ws + off); off += 4096;
  int8_t* qg  = (int8_t*)(ws + off); off += (size_t)M * H;   // 38.7 MB
  (void)ws_size; (void)n_in; (void)out_size;

  // scalar init: slots 0,1 = 0xFFFFFFFF (encoded +inf for min); 2..5 = 0
  hipMemsetAsync(sc, 0xFF, 8, stream);
  hipMemsetAsync(sc + 2, 0x00, 16, stream);

  reduce_stats<<<dim3(1280), dim3(256), 0, stream>>>(
      (const float4*)x, M * D / 4,
      (const float4*)w1, H * D / 4,
      (const float4*)w2, D * H / 4, sc);

  quant_all<<<dim3(2048 + H + D), dim3(256), 0, stream>>>(
      (const float4*)x, (unsigned*)qx, (long)M * D / 4,
      w1, w2, qw1, qw2, rs1, rs2, sc, H, D);

  // GEMM1 pass A: g min/max only
  gemm_i8<768, 0><<<dim3(H / 128, (M + 127) / 128), dim3(256), 0, stream>>>(
      qx, qw1, rs1, b1, nullptr, M, H, sc);

  // GEMM1 pass B: recompute, quantize g -> qg (int8, q-128)
  gemm_i8<768, 2><<<dim3(H / 128, (M + 127) / 128), dim3(256), 0, stream>>>(
      qx, qw1, rs1, b1, qg, M, H, sc);

  // GEMM2: out = qg @ qw2^T + b2
  gemm_i8<3072, 1><<<dim3(D / 128, (M + 127) / 128), dim3(256), 0, stream>>>(
      qg, qw2, rs2, b2, out, M, D, sc);
}

// Round 7
// 308.921 us; speedup vs baseline: 1.7502x; 1.7502x over previous
//
#include <hip/hip_runtime.h>
#include <stdint.h>
#include <stddef.h>

typedef int v4i  __attribute__((ext_vector_type(4)));
typedef int v16i __attribute__((ext_vector_type(16)));
typedef _Float16 vh8 __attribute__((ext_vector_type(8)));

#define GELU_A   (-0.2888f)
#define GELU_B   (-1.769f)
#define INV_SQRT2 0.70710678118654752440f

// async 16B global->LDS (lane i's 16B lands at ldsbase + i*16; ldsbase wave-uniform)
#define GLD16(gp, lp) __builtin_amdgcn_global_load_lds( \
    (const __attribute__((address_space(1))) unsigned int*)(gp), \
    (__attribute__((address_space(3))) unsigned int*)(lp), 16, 0, 0)

// gfx9 s_waitcnt immediates: vmcnt[3:0]=bits3:0, expcnt=bits6:4, lgkmcnt=bits11:8
#define WAIT_VM4 0x0F74   // vmcnt(4)
#define WAIT_VM0 0x0F70   // vmcnt(0)

// scalar slots: sc[0]=enc(xmin) sc[1]=enc(gmin)  [init 0xFFFFFFFF]
//               sc[2]=enc(xmax) sc[3]=|w1|max bits sc[4]=|w2|max bits sc[5]=enc(gmax) [init 0]

__device__ __forceinline__ unsigned enc_f(float f){
  unsigned u = __float_as_uint(f);
  return (u & 0x80000000u) ? ~u : (u | 0x80000000u);
}
__device__ __forceinline__ float dec_f(unsigned e){
  unsigned u = (e & 0x80000000u) ? (e & 0x7FFFFFFFu) : ~e;
  return __uint_as_float(u);
}

__device__ __forceinline__ float int_gelu_f(float x){
  float t = x * INV_SQRT2;
  float at = fminf(fabsf(t), 1.769f);
  float u = at + GELU_B;                 // in [-1.769, 0]
  float p = GELU_A * (u * u) + 1.0f;
  float L = (t > 0.0f) ? p : ((t < 0.0f) ? -p : 0.0f);
  return x * 0.5f * (1.0f + L);
}

// blocks [0,1024): x min/max; [1024,1152): absmax w1 -> sc[3]; [1152,1280): absmax w2 -> sc[4]
__global__ __launch_bounds__(256) void reduce_stats(
    const float4* __restrict__ x, int nx4,
    const float4* __restrict__ w1, int n14,
    const float4* __restrict__ w2, int n24,
    unsigned* __restrict__ sc)
{
  __shared__ float ra[256], rb[256];
  const int tid = threadIdx.x;
  const int b = blockIdx.x;
  if (b < 1024){
    float lmin = 3.4e38f, lmax = -3.4e38f;
    for (long i = (long)b * 256 + tid; i < nx4; i += 1024L * 256L){
      float4 v = x[i];
      lmin = fminf(lmin, fminf(fminf(v.x, v.y), fminf(v.z, v.w)));
      lmax = fmaxf(lmax, fmaxf(fmaxf(v.x, v.y), fmaxf(v.z, v.w)));
    }
    ra[tid] = lmin; rb[tid] = lmax;
    __syncthreads();
    for (int s = 128; s > 0; s >>= 1){
      if (tid < s){ ra[tid] = fminf(ra[tid], ra[tid + s]); rb[tid] = fmaxf(rb[tid], rb[tid + s]); }
      __syncthreads();
    }
    if (tid == 0){
      atomicMin(&sc[0], enc_f(ra[0]));
      atomicMax(&sc[2], enc_f(rb[0]));
    }
  } else {
    const float4* w; int n4; int slot; int bl;
    if (b < 1152){ w = w1; n4 = n14; slot = 3; bl = b - 1024; }
    else         { w = w2; n4 = n24; slot = 4; bl = b - 1152; }
    float la = 0.0f;
    for (long i = (long)bl * 256 + tid; i < n4; i += 128L * 256L){
      float4 v = w[i];
      la = fmaxf(la, fmaxf(fmaxf(fabsf(v.x), fabsf(v.y)), fmaxf(fabsf(v.z), fabsf(v.w))));
    }
    ra[tid] = la;
    __syncthreads();
    for (int s = 128; s > 0; s >>= 1){
      if (tid < s) ra[tid] = fmaxf(ra[tid], ra[tid + s]);
      __syncthreads();
    }
    if (tid == 0) atomicMax(&sc[slot], __float_as_uint(ra[0]));
  }
}

// fused: blocks [0,2048) act-quant x -> qx ((q-128) int8, packed u32);
//        blocks [2048, 2048+H+D) weight-quant rows (+row sums)
__global__ __launch_bounds__(256) void quant_all(
    const float4* __restrict__ x, unsigned* __restrict__ qx, long nx4,
    const float* __restrict__ w1, const float* __restrict__ w2,
    int8_t* __restrict__ qw1, int8_t* __restrict__ qw2,
    int* __restrict__ rs1, int* __restrict__ rs2,
    const unsigned* __restrict__ sc, int H, int D)
{
  const int tid = threadIdx.x;
  const int b = blockIdx.x;
  if (b < 2048){
    const float vmin = dec_f(sc[0]);
    const float vmax = dec_f(sc[2]);
    const float s  = fmaxf(vmax - vmin, 1e-8f) / 255.0f;
    const float zp = rintf(-vmin / s);
    for (long i = (long)b * 256 + tid; i < nx4; i += 2048L * 256L){
      float4 v = x[i];
      int q0 = (int)fminf(fmaxf(rintf(v.x / s) + zp, 0.0f), 255.0f) - 128;
      int q1 = (int)fminf(fmaxf(rintf(v.y / s) + zp, 0.0f), 255.0f) - 128;
      int q2 = (int)fminf(fmaxf(rintf(v.z / s) + zp, 0.0f), 255.0f) - 128;
      int q3 = (int)fminf(fmaxf(rintf(v.w / s) + zp, 0.0f), 255.0f) - 128;
      qx[i] = ((unsigned)(q0 & 255)) | ((unsigned)(q1 & 255) << 8) |
              ((unsigned)(q2 & 255) << 16) | ((unsigned)(q3 & 255) << 24);
    }
  } else {
    __shared__ int red[256];
    const int wb = b - 2048;
    const float* w; int8_t* q; int* rs; int K; int n; float s;
    if (wb < H){ w = w1; q = qw1; rs = rs1; K = D; n = wb;
                 s = fmaxf(__uint_as_float(sc[3]), 1e-8f) / 127.0f; }
    else       { w = w2; q = qw2; rs = rs2; K = H; n = wb - H;
                 s = fmaxf(__uint_as_float(sc[4]), 1e-8f) / 127.0f; }
    int sum = 0;
    for (int k = tid; k < K; k += 256){
      float v = w[(size_t)n * K + k];
      float qf = fminf(fmaxf(rintf(v / s), -128.0f), 127.0f);
      int qi = (int)qf;
      q[(size_t)n * K + k] = (int8_t)qi;
      sum += qi;
    }
    red[tid] = sum;
    __syncthreads();
    for (int st = 128; st > 0; st >>= 1){
      if (tid < st) red[tid] += red[tid + st];
      __syncthreads();
    }
    if (tid == 0) rs[n] = red[0];
  }
}

// elementwise: fp16 g -> int8 qg ((q-128)), using g stats
__global__ __launch_bounds__(256) void quant_g(
    const vh8* __restrict__ g, uint2* __restrict__ qg, long n8,
    const unsigned* __restrict__ sc)
{
  const float gmin = dec_f(sc[1]), gmax = dec_f(sc[5]);
  const float qs  = fmaxf(gmax - gmin, 1e-8f) / 255.0f;
  const float qzp = rintf(-gmin / qs);
  const long stride = (long)gridDim.x * blockDim.x;
  for (long i = (long)blockIdx.x * blockDim.x + threadIdx.x; i < n8; i += stride){
    vh8 v = g[i];
    unsigned lo = 0, hi = 0;
#pragma unroll
    for (int j = 0; j < 4; j++){
      int q = (int)fminf(fmaxf(rintf((float)v[j] / qs) + qzp, 0.0f), 255.0f) - 128;
      lo |= ((unsigned)(q & 255)) << (8 * j);
    }
#pragma unroll
    for (int j = 0; j < 4; j++){
      int q = (int)fminf(fmaxf(rintf((float)v[4 + j] / qs) + qzp, 0.0f), 255.0f) - 128;
      hi |= ((unsigned)(q & 255)) << (8 * j);
    }
    uint2 o; o.x = lo; o.y = hi;
    qg[i] = o;
  }
}

// MODE 0: h->gelu-> g min/max atomics only (no store)          [fallback pass A]
// MODE 3: h->gelu-> store g fp16 + g min/max atomics            [main pass A]
// MODE 2: h->gelu-> quantize with g stats -> store int8 (q-128) [fallback pass B]
// MODE 1: h + bias -> store fp32 out                            [GEMM2]
//
// 128x128 tile, BK=64, mfma_i32_32x32x32_i8, 4 waves each 64x64 (2x2 of 32x32).
// 3-stage software pipeline, 3 LDS buffers (48KB -> 3 blocks/CU); per iter:
// s_waitcnt vmcnt(4) (own tile-kt DMAs done, kt+1's in flight) -> raw s_barrier
// -> ds_read frags -> issue DMA kt+2 -> MFMAs. Never vmcnt(0) in steady state.
template<int MODE>
__global__ __launch_bounds__(256) void gemm_i8(
    const int8_t* __restrict__ A, const int8_t* __restrict__ Bm,
    const int* __restrict__ rowsum, const float* __restrict__ bias,
    void* __restrict__ Cout, int M, int N, int K,
    unsigned* __restrict__ sc)
{
  __shared__ __align__(16) int8_t lds[3][16384];   // per buf: A @0, B @8192

  const int tid  = threadIdx.x;
  const int lane = tid & 63;
  const int wave = tid >> 6;
  const int l31  = lane & 31;
  const int kh   = lane >> 5;          // 0/1 : which 16B half of a 32-k block
  const int n0   = blockIdx.x * 128;
  const int m0   = blockIdx.y * 128;
  const int wm   = (wave & 1) * 64;
  const int wn   = (wave >> 1) * 64;

  // staging: wave w stages tile rows [32w,32w+32), 2 instrs of 16 rows each per
  // operand. lane L -> row rbase+(L>>2), LDS slot L&3, src chunk (L&3)^((row>>1)&3).
  int aoffs[2], boffs[2];
  const int ldst[2] = { wave * 2048, wave * 2048 + 1024 };
#pragma unroll
  for (int t = 0; t < 2; t++){
    int rowl = wave * 32 + t * 16 + (lane >> 2);       // local tile row 0..127
    int csw  = ((lane & 3) ^ ((rowl >> 1) & 3)) << 4;  // swizzled source chunk
    int ga = m0 + rowl; if (ga >= M) ga = M - 1;
    aoffs[t] = ga * K + csw;
    boffs[t] = (n0 + rowl) * K + csw;
  }

  // fragment read constants: slot s = (kk*2+kh) ^ ((l31>>1)&3)
  const int w2  = (l31 >> 1) & 3;
  const int sA0 = (kh ^ w2) << 4;
  int arow[2], brow[2];
#pragma unroll
  for (int mi = 0; mi < 2; mi++){
    arow[mi] = (wm + mi * 32 + l31) * 64;
    brow[mi] = (wn + mi * 32 + l31) * 64;
  }

  v16i acc[2][2] = {};
  const int NT = K >> 6;

  // prologue: stage tiles 0,1 into bufs 0,1 (issue order = vmcnt order)
#pragma unroll
  for (int t = 0; t < 2; t++){
    GLD16(A  + aoffs[t],      &lds[0][ldst[t]]);
    GLD16(Bm + boffs[t],      &lds[0][8192 + ldst[t]]);
  }
#pragma unroll
  for (int t = 0; t < 2; t++){
    GLD16(A  + aoffs[t] + 64, &lds[1][ldst[t]]);
    GLD16(Bm + boffs[t] + 64, &lds[1][8192 + ldst[t]]);
  }

  for (int kt = 0; kt < NT; kt++){
    const int8_t* buf = lds[kt % 3];
    if (kt + 1 < NT) __builtin_amdgcn_s_waitcnt(WAIT_VM4);
    else             __builtin_amdgcn_s_waitcnt(WAIT_VM0);
    __builtin_amdgcn_s_barrier();          // raw: no compiler vmcnt(0) fence
    __builtin_amdgcn_sched_barrier(0);     // nothing (esp. next DMA) crosses up

    v4i af[2][2], bf[2][2];                // [kk][mi]
#pragma unroll
    for (int kk = 0; kk < 2; kk++){
      const int sb = sA0 ^ (kk << 5);
#pragma unroll
      for (int mi = 0; mi < 2; mi++){
        af[kk][mi] = *(const v4i*)(buf + arow[mi] + sb);
        bf[kk][mi] = *(const v4i*)(buf + 8192 + brow[mi] + sb);
      }
    }

    if (kt + 2 < NT){                      // prefetch distance 2
      int8_t* nbuf = lds[(kt + 2) % 3];
      const int ko = (kt + 2) << 6;
#pragma unroll
      for (int t = 0; t < 2; t++){
        GLD16(A  + aoffs[t] + ko, nbuf + ldst[t]);
        GLD16(Bm + boffs[t] + ko, nbuf + 8192 + ldst[t]);
      }
    }

#pragma unroll
    for (int kk = 0; kk < 2; kk++)
#pragma unroll
      for (int mi = 0; mi < 2; mi++)
#pragma unroll
        for (int nj = 0; nj < 2; nj++)
          acc[mi][nj] = __builtin_amdgcn_mfma_i32_32x32x32_i8(af[kk][mi], bf[kk][nj], acc[mi][nj], 0, 0, 0);
  }

  // epilogue scalars
  float s_h, off_h;
  if constexpr (MODE == 1){
    float gmin = dec_f(sc[1]), gmax = dec_f(sc[5]);
    float sg = fmaxf(gmax - gmin, 1e-8f) / 255.0f;
    float zp = rintf(-gmin / sg);
    float sw = fmaxf(__uint_as_float(sc[4]), 1e-8f) / 127.0f;
    s_h = sg * sw; off_h = 128.0f - zp;
  } else {
    float xmin = dec_f(sc[0]), xmax = dec_f(sc[2]);
    float sx = fmaxf(xmax - xmin, 1e-8f) / 255.0f;
    float zp = rintf(-xmin / sx);
    float sw = fmaxf(__uint_as_float(sc[3]), 1e-8f) / 127.0f;
    s_h = sx * sw; off_h = 128.0f - zp;
  }
  float qs = 1.0f, qzp = 0.0f;
  if constexpr (MODE == 2){
    float gmin = dec_f(sc[1]), gmax = dec_f(sc[5]);
    qs = fmaxf(gmax - gmin, 1e-8f) / 255.0f;
    qzp = rintf(-gmin / qs);
  }

  // C/D 32x32 layout: col = lane&31, row = (reg&3) + 8*(reg>>2) + 4*(lane>>5)
  float lmin = 3.4e38f, lmax = -3.4e38f;
#pragma unroll
  for (int nj = 0; nj < 2; nj++){
    const int n = n0 + wn + nj * 32 + l31;
    const float rsv = off_h * (float)rowsum[n];
    const float bv = bias[n];
#pragma unroll
    for (int mi = 0; mi < 2; mi++){
      const int mbase = m0 + wm + mi * 32 + 4 * kh;
#pragma unroll
      for (int r = 0; r < 16; r++){
        const int m = mbase + (r & 3) + 8 * (r >> 2);
        if (m < M){
          float h = s_h * ((float)acc[mi][nj][r] + rsv) + bv;
          if constexpr (MODE == 0){
            float gv = int_gelu_f(h);
            lmin = fminf(lmin, gv); lmax = fmaxf(lmax, gv);
          } else if constexpr (MODE == 3){
            float gv = int_gelu_f(h);
            lmin = fminf(lmin, gv); lmax = fmaxf(lmax, gv);
            ((_Float16*)Cout)[(size_t)m * N + n] = (_Float16)gv;
          } else if constexpr (MODE == 2){
            float gv = int_gelu_f(h);
            float qf = fminf(fmaxf(rintf(gv / qs) + qzp, 0.0f), 255.0f);
            ((int8_t*)Cout)[(size_t)m * N + n] = (int8_t)((int)qf - 128);
          } else {
            ((float*)Cout)[(size_t)m * N + n] = h;
          }
        }
      }
    }
  }

  if constexpr (MODE == 0 || MODE == 3){
    __syncthreads();                   // all waves done with LDS -> reuse as scratch
    float* redA = (float*)&lds[0][0];
    float* redB = ((float*)&lds[0][0]) + 256;
    redA[tid] = lmin; redB[tid] = lmax;
    __syncthreads();
    for (int st = 128; st > 0; st >>= 1){
      if (tid < st){
        redA[tid] = fminf(redA[tid], redA[tid + st]);
        redB[tid] = fmaxf(redB[tid], redB[tid + st]);
      }
      __syncthreads();
    }
    if (tid == 0){
      atomicMin(&sc[1], enc_f(redA[0]));
      atomicMax(&sc[5], enc_f(redB[0]));
    }
  }
}

extern "C" void kernel_launch(void* const* d_in, const int* in_sizes, int n_in,
                              void* d_out, int out_size, void* d_ws, size_t ws_size,
                              hipStream_t stream)
{
  const float* x  = (const float*)d_in[0];
  const float* w1 = (const float*)d_in[1];
  const float* b1 = (const float*)d_in[2];
  const float* w2 = (const float*)d_in[3];
  const float* b2 = (const float*)d_in[4];
  float* out = (float*)d_out;

  const int H = in_sizes[2];            // 3072
  const int D = in_sizes[4];            // 768
  const int M = in_sizes[0] / D;        // 12608

  char* ws = (char*)d_ws;
  unsigned* sc = (unsigned*)ws;
  size_t off = 256;
  int8_t* qx  = (int8_t*)(ws + off); off += (size_t)M * D;   // 9.68 MB
  int8_t* qw1 = (int8_t*)(ws + off); off += (size_t)H * D;   // 2.36 MB
  int8_t* qw2 = (int8_t*)(ws + off); off += (size_t)D * H;   // 2.36 MB
  int* rs1 = (int*)(ws + off); off += (size_t)H * 4;
  int* rs2 = (int*)(ws + off); off += 4096;
  int8_t* qg  = (int8_t*)(ws + off); off += (size_t)M * H;   // 38.7 MB
  _Float16* g16 = (_Float16*)(ws + off);                      // 77.5 MB (big path)
  const size_t need_big = off + (size_t)M * H * 2;
  (void)n_in; (void)out_size;

  // scalar init: slots 0,1 = 0xFFFFFFFF (encoded +inf for min); 2..5 = 0
  hipMemsetAsync(sc, 0xFF, 8, stream);
  hipMemsetAsync(sc + 2, 0x00, 16, stream);

  reduce_stats<<<dim3(1280), dim3(256), 0, stream>>>(
      (const float4*)x, M * D / 4,
      (const float4*)w1, H * D / 4,
      (const float4*)w2, D * H / 4, sc);

  quant_all<<<dim3(2048 + H + D), dim3(256), 0, stream>>>(
      (const float4*)x, (unsigned*)qx, (long)M * D / 4,
      w1, w2, qw1, qw2, rs1, rs2, sc, H, D);

  const dim3 g1(H / 128, (M + 127) / 128), g2(D / 128, (M + 127) / 128), blk(256);

  if (ws_size >= need_big){
    // GEMM1 (single pass): g stats + store g fp16
    gemm_i8<3><<<g1, blk, 0, stream>>>(qx, qw1, rs1, b1, g16, M, H, D, sc);
    // elementwise quantize g -> qg
    quant_g<<<dim3(2048), blk, 0, stream>>>(
        (const vh8*)g16, (uint2*)qg, (long)M * H / 8, sc);
  } else {
    // fallback: exact 2-pass GEMM1 (stats, then quantize)
    gemm_i8<0><<<g1, blk, 0, stream>>>(qx, qw1, rs1, b1, nullptr, M, H, D, sc);
    gemm_i8<2><<<g1, blk, 0, stream>>>(qx, qw1, rs1, b1, qg, M, H, D, sc);
  }

  // GEMM2: out = qg @ qw2^T + b2
  gemm_i8<1><<<g2, blk, 0, stream>>>(qg, qw2, rs2, b2, out, M, D, H, sc);
}